// Round 4
// baseline (367.524 us; speedup 1.0000x reference)
//
// R3: never launch an empty graph. Runtime ws_size dispatch:
//   A (ws>=88M+64K): full 2-GEMM bf16 MFMA pipeline
//   B (ws>=56M+64K): same kernels, Q-chunked x4
//   D (else)       : zero-ws fused fp32 fallback (slow, correct, diagnostic)
#include <hip/hip_runtime.h>

#define NQ 4096
#define NK 8192
#define DIM 1024

typedef __attribute__((ext_vector_type(8))) short short8;
typedef __attribute__((ext_vector_type(4))) float floatx4;

__device__ __forceinline__ unsigned short f32_bf16(float f) {
    unsigned int u = __float_as_uint(f);
    u += 0x7fff + ((u >> 16) & 1);   // round-to-nearest-even
    return (unsigned short)(u >> 16);
}

// ---------------------------------------------------------------------------
// prep: per-row 1/norm, fp32 -> bf16 conversion, optional zero of lsum
// ---------------------------------------------------------------------------
__global__ void prep_norm_cvt(const float* __restrict__ src,
                              unsigned short* __restrict__ dst,
                              float* __restrict__ inv_norm,
                              float* __restrict__ zero_arr) {
    int wave = threadIdx.x >> 6;
    int lane = threadIdx.x & 63;
    int row  = blockIdx.x * 4 + wave;
    const float* r = src + (size_t)row * DIM;
    float s = 0.f;
#pragma unroll
    for (int c = 0; c < 4; ++c) {
        float4 f = *(const float4*)(r + c * 256 + lane * 4);
        s += f.x * f.x + f.y * f.y + f.z * f.z + f.w * f.w;
        ushort4 b;
        b.x = f32_bf16(f.x); b.y = f32_bf16(f.y);
        b.z = f32_bf16(f.z); b.w = f32_bf16(f.w);
        *(ushort4*)(dst + (size_t)row * DIM + c * 256 + lane * 4) = b;
    }
#pragma unroll
    for (int off = 32; off > 0; off >>= 1) s += __shfl_xor(s, off);
    if (lane == 0) {
        inv_norm[row] = 1.0f / sqrtf(s);
        if (zero_arr) zero_arr[row] = 0.f;
    }
}

// ---------------------------------------------------------------------------
// transpose + convert: Kt[d][kn] = bf16(K[kn][d]); 64x64 tiles
// ---------------------------------------------------------------------------
__global__ void transpose_cvt(const float* __restrict__ K,
                              unsigned short* __restrict__ Kt) {
    __shared__ float t[64][65];
    int kn0 = blockIdx.x * 64, d0 = blockIdx.y * 64;
    int tid = threadIdx.x;
    int r  = tid >> 4;
    int c4 = (tid & 15) * 4;
#pragma unroll
    for (int s = 0; s < 4; ++s) {
        int kk = s * 16 + r;
        float4 f = *(const float4*)(K + (size_t)(kn0 + kk) * DIM + d0 + c4);
        t[kk][c4 + 0] = f.x; t[kk][c4 + 1] = f.y;
        t[kk][c4 + 2] = f.z; t[kk][c4 + 3] = f.w;
    }
    __syncthreads();
#pragma unroll
    for (int s = 0; s < 4; ++s) {
        int dd = s * 16 + r;
        ushort4 b;
        b.x = f32_bf16(t[c4 + 0][dd]);
        b.y = f32_bf16(t[c4 + 1][dd]);
        b.z = f32_bf16(t[c4 + 2][dd]);
        b.w = f32_bf16(t[c4 + 3][dd]);
        *(ushort4*)(Kt + (size_t)(d0 + dd) * NK + kn0 + c4) = b;
    }
}

// ---------------------------------------------------------------------------
// GEMM 1: S = Q·K^T scaled to cosine, P = exp(S) (bf16), lsum += rowsum(P)
// cosine in [-1,1] => exp without max-subtract is safe.
// ---------------------------------------------------------------------------
#define PITCH 40

__global__ void score_gemm(const unsigned short* __restrict__ Qb,
                           const unsigned short* __restrict__ Kb,
                           const float* __restrict__ inv_qn,
                           const float* __restrict__ inv_kn,
                           unsigned short* __restrict__ P,
                           float* __restrict__ lsum) {
    __shared__ __align__(16) unsigned short As[128 * PITCH];
    __shared__ __align__(16) unsigned short Bs[128 * PITCH];
    int q0 = blockIdx.y * 128;
    int n0 = blockIdx.x * 128;
    int tid = threadIdx.x;
    int wave = tid >> 6, lane = tid & 63;
    int wm = wave >> 1, wn = wave & 1;
    int quad = lane >> 4, l16 = lane & 15;

    floatx4 acc[4][4];
#pragma unroll
    for (int i = 0; i < 4; ++i)
#pragma unroll
        for (int j = 0; j < 4; ++j) acc[i][j] = (floatx4)(0.0f);

    for (int kb = 0; kb < DIM / 32; ++kb) {
        int d0 = kb * 32;
        __syncthreads();
#pragma unroll
        for (int s = 0; s < 2; ++s) {
            int c = s * 256 + tid;
            int row = c >> 2, col = (c & 3) * 8;
            *(short8*)&As[row * PITCH + col] =
                *(const short8*)(Qb + (size_t)(q0 + row) * DIM + d0 + col);
            *(short8*)&Bs[row * PITCH + col] =
                *(const short8*)(Kb + (size_t)(n0 + row) * DIM + d0 + col);
        }
        __syncthreads();
        short8 a[4], b[4];
#pragma unroll
        for (int i = 0; i < 4; ++i)
            a[i] = *(const short8*)&As[(wm * 64 + i * 16 + l16) * PITCH + quad * 8];
#pragma unroll
        for (int j = 0; j < 4; ++j)
            b[j] = *(const short8*)&Bs[(wn * 64 + j * 16 + l16) * PITCH + quad * 8];
#pragma unroll
        for (int i = 0; i < 4; ++i)
#pragma unroll
            for (int j = 0; j < 4; ++j)
                acc[i][j] = __builtin_amdgcn_mfma_f32_16x16x32_bf16(a[i], b[j], acc[i][j], 0, 0, 0);
    }

#pragma unroll
    for (int i = 0; i < 4; ++i) {
        float iqn[4], rs[4];
#pragma unroll
        for (int r = 0; r < 4; ++r) {
            iqn[r] = inv_qn[q0 + wm * 64 + i * 16 + quad * 4 + r];
            rs[r] = 0.f;
        }
#pragma unroll
        for (int j = 0; j < 4; ++j) {
            int col = n0 + wn * 64 + j * 16 + l16;
            float ikn = inv_kn[col];
#pragma unroll
            for (int r = 0; r < 4; ++r) {
                int qrow = q0 + wm * 64 + i * 16 + quad * 4 + r;
                float sc = acc[i][j][r] * iqn[r] * ikn;
                float p = __expf(sc);
                P[(size_t)qrow * NK + col] = f32_bf16(p);
                rs[r] += p;
            }
        }
#pragma unroll
        for (int r = 0; r < 4; ++r) {
            float v = rs[r];
            v += __shfl_xor(v, 1);
            v += __shfl_xor(v, 2);
            v += __shfl_xor(v, 4);
            v += __shfl_xor(v, 8);
            if (l16 == 0)
                atomicAdd(&lsum[q0 + wm * 64 + i * 16 + quad * 4 + r], v);
        }
    }
}

// ---------------------------------------------------------------------------
// GEMM 2: out = (P · V) / lsum
// ---------------------------------------------------------------------------
__global__ void ctx_gemm(const unsigned short* __restrict__ P,
                         const unsigned short* __restrict__ Kt,
                         const float* __restrict__ lsum,
                         float* __restrict__ out) {
    __shared__ __align__(16) unsigned short As[128 * PITCH];
    __shared__ __align__(16) unsigned short Bs[128 * PITCH];
    int q0 = blockIdx.y * 128;
    int d0 = blockIdx.x * 128;
    int tid = threadIdx.x;
    int wave = tid >> 6, lane = tid & 63;
    int wm = wave >> 1, wn = wave & 1;
    int quad = lane >> 4, l16 = lane & 15;

    floatx4 acc[4][4];
#pragma unroll
    for (int i = 0; i < 4; ++i)
#pragma unroll
        for (int j = 0; j < 4; ++j) acc[i][j] = (floatx4)(0.0f);

    for (int nb = 0; nb < NK / 32; ++nb) {
        int k0 = nb * 32;
        __syncthreads();
#pragma unroll
        for (int s = 0; s < 2; ++s) {
            int c = s * 256 + tid;
            int row = c >> 2, col = (c & 3) * 8;
            *(short8*)&As[row * PITCH + col] =
                *(const short8*)(P + (size_t)(q0 + row) * NK + k0 + col);
            *(short8*)&Bs[row * PITCH + col] =
                *(const short8*)(Kt + (size_t)(d0 + row) * NK + k0 + col);
        }
        __syncthreads();
        short8 a[4], b[4];
#pragma unroll
        for (int i = 0; i < 4; ++i)
            a[i] = *(const short8*)&As[(wm * 64 + i * 16 + l16) * PITCH + quad * 8];
#pragma unroll
        for (int j = 0; j < 4; ++j)
            b[j] = *(const short8*)&Bs[(wn * 64 + j * 16 + l16) * PITCH + quad * 8];
#pragma unroll
        for (int i = 0; i < 4; ++i)
#pragma unroll
            for (int j = 0; j < 4; ++j)
                acc[i][j] = __builtin_amdgcn_mfma_f32_16x16x32_bf16(a[i], b[j], acc[i][j], 0, 0, 0);
    }

#pragma unroll
    for (int i = 0; i < 4; ++i) {
        float invl[4];
#pragma unroll
        for (int r = 0; r < 4; ++r)
            invl[r] = 1.0f / lsum[q0 + wm * 64 + i * 16 + quad * 4 + r];
#pragma unroll
        for (int j = 0; j < 4; ++j) {
#pragma unroll
            for (int r = 0; r < 4; ++r) {
                int qrow = q0 + wm * 64 + i * 16 + quad * 4 + r;
                int dcol = d0 + wn * 64 + j * 16 + l16;
                out[(size_t)qrow * DIM + dcol] = acc[i][j][r] * invl[r];
            }
        }
    }
}

// ---------------------------------------------------------------------------
// Path D: zero-workspace fused fp32 fallback. One wave = 4 Q rows, single
// online pass over all 8192 keys (cosine in [-1,1] => no max needed).
// Slow (~2 ms) but correct; also a ws_size diagnostic.
// ---------------------------------------------------------------------------
__global__ void fused_fallback(const float* __restrict__ Q,
                               const float* __restrict__ K,
                               float* __restrict__ out) {
    int wave = threadIdx.x >> 6, lane = threadIdx.x & 63;
    int q0 = blockIdx.x * 16 + wave * 4;   // 4 rows per wave

    float qv[4][16], acc[4][16], iqn[4], ls[4];
#pragma unroll
    for (int r = 0; r < 4; ++r) {
        float s = 0.f;
#pragma unroll
        for (int c = 0; c < 4; ++c) {
            float4 f = *(const float4*)(Q + (size_t)(q0 + r) * DIM + c * 256 + lane * 4);
            qv[r][c * 4 + 0] = f.x; qv[r][c * 4 + 1] = f.y;
            qv[r][c * 4 + 2] = f.z; qv[r][c * 4 + 3] = f.w;
            s += f.x * f.x + f.y * f.y + f.z * f.z + f.w * f.w;
        }
#pragma unroll
        for (int off = 32; off > 0; off >>= 1) s += __shfl_xor(s, off);
        iqn[r] = 1.0f / sqrtf(s);
        ls[r] = 0.f;
#pragma unroll
        for (int t = 0; t < 16; ++t) acc[r][t] = 0.f;
    }

    for (int k = 0; k < NK; ++k) {
        const float* kr = K + (size_t)k * DIM;
        float kv[16], ss = 0.f;
#pragma unroll
        for (int c = 0; c < 4; ++c) {
            float4 f = *(const float4*)(kr + c * 256 + lane * 4);
            kv[c * 4 + 0] = f.x; kv[c * 4 + 1] = f.y;
            kv[c * 4 + 2] = f.z; kv[c * 4 + 3] = f.w;
            ss += f.x * f.x + f.y * f.y + f.z * f.z + f.w * f.w;
        }
        float d0 = 0.f, d1 = 0.f, d2 = 0.f, d3 = 0.f;
#pragma unroll
        for (int t = 0; t < 16; ++t) {
            d0 += qv[0][t] * kv[t];
            d1 += qv[1][t] * kv[t];
            d2 += qv[2][t] * kv[t];
            d3 += qv[3][t] * kv[t];
        }
#pragma unroll
        for (int off = 32; off > 0; off >>= 1) {
            ss += __shfl_xor(ss, off);
            d0 += __shfl_xor(d0, off);
            d1 += __shfl_xor(d1, off);
            d2 += __shfl_xor(d2, off);
            d3 += __shfl_xor(d3, off);
        }
        float ikn = 1.0f / sqrtf(ss);
        float p0 = __expf(d0 * iqn[0] * ikn);
        float p1 = __expf(d1 * iqn[1] * ikn);
        float p2 = __expf(d2 * iqn[2] * ikn);
        float p3 = __expf(d3 * iqn[3] * ikn);
        ls[0] += p0; ls[1] += p1; ls[2] += p2; ls[3] += p3;
#pragma unroll
        for (int t = 0; t < 16; ++t) {
            acc[0][t] += p0 * kv[t];
            acc[1][t] += p1 * kv[t];
            acc[2][t] += p2 * kv[t];
            acc[3][t] += p3 * kv[t];
        }
    }

#pragma unroll
    for (int r = 0; r < 4; ++r) {
        float inv = 1.0f / ls[r];
#pragma unroll
        for (int c = 0; c < 4; ++c) {
            float4 o;
            o.x = acc[r][c * 4 + 0] * inv; o.y = acc[r][c * 4 + 1] * inv;
            o.z = acc[r][c * 4 + 2] * inv; o.w = acc[r][c * 4 + 3] * inv;
            *(float4*)(out + (size_t)(q0 + r) * DIM + c * 256 + lane * 4) = o;
        }
    }
}

// ---------------------------------------------------------------------------
// launch — dispatch on ws_size; ALWAYS launches work (no empty graph).
// ---------------------------------------------------------------------------
extern "C" void kernel_launch(void* const* d_in, const int* in_sizes, int n_in,
                              void* d_out, int out_size, void* d_ws, size_t ws_size,
                              hipStream_t stream) {
    const float* Q = (const float*)d_in[0];   // [4096,1024]
    const float* K = (const float*)d_in[1];   // [8192,1024]
    float* out = (float*)d_out;               // [4096,1024]
    char* ws = (char*)d_ws;

    const size_t REQ_A = ((size_t)88u << 20) + 65536;
    const size_t REQ_B = ((size_t)56u << 20) + 65536;

    if (ws_size >= REQ_A) {
        // Path A: Kt overlaps Qb/Kb (dead after score_gemm)
        unsigned short* Kt = (unsigned short*)(ws);
        unsigned short* Qb = (unsigned short*)(ws);
        unsigned short* Kb = (unsigned short*)(ws + (size_t)(8u << 20));
        unsigned short* P  = (unsigned short*)(ws + (size_t)(24u << 20));
        float* inv_qn = (float*)(ws + (size_t)(88u << 20));
        float* inv_kn = (float*)(ws + (size_t)(88u << 20) + 16384);
        float* lsum   = (float*)(ws + (size_t)(88u << 20) + 49152);

        prep_norm_cvt<<<NQ / 4, 256, 0, stream>>>(Q, Qb, inv_qn, lsum);
        prep_norm_cvt<<<NK / 4, 256, 0, stream>>>(K, Kb, inv_kn, nullptr);
        score_gemm<<<dim3(NK / 128, NQ / 128), 256, 0, stream>>>(Qb, Kb, inv_qn, inv_kn, P, lsum);
        transpose_cvt<<<dim3(NK / 64, DIM / 64), 256, 0, stream>>>(K, Kt);
        ctx_gemm<<<dim3(DIM / 128, NQ / 128), 256, 0, stream>>>(P, Kt, lsum, out);
    } else if (ws_size >= REQ_B) {
        // Path B: Q-chunked x4, P is 1024 x NK (16 MB), all buffers disjoint
        unsigned short* Qb = (unsigned short*)(ws);                        //  8 MB
        unsigned short* Kb = (unsigned short*)(ws + (size_t)(8u << 20));   // 16 MB
        unsigned short* Kt = (unsigned short*)(ws + (size_t)(24u << 20));  // 16 MB
        unsigned short* P  = (unsigned short*)(ws + (size_t)(40u << 20));  // 16 MB
        float* inv_qn = (float*)(ws + (size_t)(56u << 20));
        float* inv_kn = (float*)(ws + (size_t)(56u << 20) + 16384);
        float* lsum   = (float*)(ws + (size_t)(56u << 20) + 49152);

        prep_norm_cvt<<<NQ / 4, 256, 0, stream>>>(Q, Qb, inv_qn, lsum);
        prep_norm_cvt<<<NK / 4, 256, 0, stream>>>(K, Kb, inv_kn, nullptr);
        transpose_cvt<<<dim3(NK / 64, DIM / 64), 256, 0, stream>>>(K, Kt);
        for (int c = 0; c < 4; ++c) {
            size_t qoff = (size_t)c * 1024;
            score_gemm<<<dim3(NK / 128, 1024 / 128), 256, 0, stream>>>(
                Qb + qoff * DIM, Kb, inv_qn + qoff, inv_kn, P, lsum + qoff);
            ctx_gemm<<<dim3(DIM / 128, 1024 / 128), 256, 0, stream>>>(
                P, Kt, lsum + qoff, out + qoff * DIM);
        }
    } else {
        // Path D: zero-workspace fallback (also tells us ws_size < 56 MB)
        fused_fallback<<<NQ / 16, 256, 0, stream>>>(Q, K, out);
    }
}

// Round 5
// 338.051 us; speedup vs baseline: 1.0872x; 1.0872x over previous
//
// R5: (1) global_load_lds width-16 staging in both GEMMs (m97 ladder step),
//     (2) ctx_gemm split-K x4 via atomicAdd (fixes 1-block/CU occupancy),
//     (3) zero_out kernel for the atomic accumulation target.
#include <hip/hip_runtime.h>

#define NQ 4096
#define NK 8192
#define DIM 1024

typedef __attribute__((ext_vector_type(8))) short short8;
typedef __attribute__((ext_vector_type(4))) float floatx4;
typedef unsigned int u32;
typedef __attribute__((address_space(3))) u32 lds_u32;
typedef __attribute__((address_space(1))) const u32 glb_u32;

__device__ __forceinline__ void gload_lds16(const void* g, void* l) {
    // async global->LDS, 16B/lane; LDS dest = wave-uniform base + lane*16
    __builtin_amdgcn_global_load_lds((glb_u32*)g, (lds_u32*)l, 16, 0, 0);
}

__device__ __forceinline__ unsigned short f32_bf16(float f) {
    unsigned int u = __float_as_uint(f);
    u += 0x7fff + ((u >> 16) & 1);   // round-to-nearest-even
    return (unsigned short)(u >> 16);
}

// ---------------------------------------------------------------------------
// zero the atomic-accumulation output (harness poisons d_out with 0xAA)
// ---------------------------------------------------------------------------
__global__ void zero_out(float* __restrict__ out) {
    size_t i = (size_t)blockIdx.x * 256 + threadIdx.x;
    *(float4*)(out + i * 4) = make_float4(0.f, 0.f, 0.f, 0.f);
}

// ---------------------------------------------------------------------------
// prep: per-row 1/norm, fp32 -> bf16, optional zero of lsum
// ---------------------------------------------------------------------------
__global__ void prep_norm_cvt(const float* __restrict__ src,
                              unsigned short* __restrict__ dst,
                              float* __restrict__ inv_norm,
                              float* __restrict__ zero_arr) {
    int wave = threadIdx.x >> 6;
    int lane = threadIdx.x & 63;
    int row  = blockIdx.x * 4 + wave;
    const float* r = src + (size_t)row * DIM;
    float s = 0.f;
#pragma unroll
    for (int c = 0; c < 4; ++c) {
        float4 f = *(const float4*)(r + c * 256 + lane * 4);
        s += f.x * f.x + f.y * f.y + f.z * f.z + f.w * f.w;
        ushort4 b;
        b.x = f32_bf16(f.x); b.y = f32_bf16(f.y);
        b.z = f32_bf16(f.z); b.w = f32_bf16(f.w);
        *(ushort4*)(dst + (size_t)row * DIM + c * 256 + lane * 4) = b;
    }
#pragma unroll
    for (int off = 32; off > 0; off >>= 1) s += __shfl_xor(s, off);
    if (lane == 0) {
        inv_norm[row] = 1.0f / sqrtf(s);
        if (zero_arr) zero_arr[row] = 0.f;
    }
}

// ---------------------------------------------------------------------------
// transpose + convert: Kt[d][kn] = bf16(K[kn][d]); 64x64 tiles
// ---------------------------------------------------------------------------
__global__ void transpose_cvt(const float* __restrict__ K,
                              unsigned short* __restrict__ Kt) {
    __shared__ float t[64][65];
    int kn0 = blockIdx.x * 64, d0 = blockIdx.y * 64;
    int tid = threadIdx.x;
    int r  = tid >> 4;
    int c4 = (tid & 15) * 4;
#pragma unroll
    for (int s = 0; s < 4; ++s) {
        int kk = s * 16 + r;
        float4 f = *(const float4*)(K + (size_t)(kn0 + kk) * DIM + d0 + c4);
        t[kk][c4 + 0] = f.x; t[kk][c4 + 1] = f.y;
        t[kk][c4 + 2] = f.z; t[kk][c4 + 3] = f.w;
    }
    __syncthreads();
#pragma unroll
    for (int s = 0; s < 4; ++s) {
        int dd = s * 16 + r;
        ushort4 b;
        b.x = f32_bf16(t[c4 + 0][dd]);
        b.y = f32_bf16(t[c4 + 1][dd]);
        b.z = f32_bf16(t[c4 + 2][dd]);
        b.w = f32_bf16(t[c4 + 3][dd]);
        *(ushort4*)(Kt + (size_t)(d0 + dd) * NK + kn0 + c4) = b;
    }
}

// ---------------------------------------------------------------------------
// GEMM 1: P = exp(cosine(Q,K)) bf16, lsum += rowsum(P).
// 128x128 tile, BK=32, global_load_lds staging (unpadded 128x32 LDS tiles):
// wave w stages rows [32w,32w+32) in two 16-row issues; lane l -> row +l/4,
// 16B chunk l%4; HW writes lane l to ldsbase + l*16 => row-major unpadded.
// ---------------------------------------------------------------------------
__global__ void score_gemm(const unsigned short* __restrict__ Qb,
                           const unsigned short* __restrict__ Kb,
                           const float* __restrict__ inv_qn,
                           const float* __restrict__ inv_kn,
                           unsigned short* __restrict__ P,
                           float* __restrict__ lsum) {
    __shared__ __align__(16) unsigned short As[128 * 32];
    __shared__ __align__(16) unsigned short Bs[128 * 32];
    int q0 = blockIdx.y * 128;
    int n0 = blockIdx.x * 128;
    int tid = threadIdx.x;
    int wave = tid >> 6, lane = tid & 63;
    int wm = wave >> 1, wn = wave & 1;
    int quad = lane >> 4, l16 = lane & 15;

    int srow   = wave * 32 + (lane >> 2);
    int schunk = (lane & 3) * 8;
    const unsigned short* gA0 = Qb + (size_t)(q0 + srow) * DIM + schunk;
    const unsigned short* gA1 = gA0 + (size_t)16 * DIM;
    const unsigned short* gB0 = Kb + (size_t)(n0 + srow) * DIM + schunk;
    const unsigned short* gB1 = gB0 + (size_t)16 * DIM;
    unsigned short* lA0 = As + wave * 32 * 32;   // wave-uniform LDS bases
    unsigned short* lA1 = lA0 + 16 * 32;
    unsigned short* lB0 = Bs + wave * 32 * 32;
    unsigned short* lB1 = lB0 + 16 * 32;

    floatx4 acc[4][4];
#pragma unroll
    for (int i = 0; i < 4; ++i)
#pragma unroll
        for (int j = 0; j < 4; ++j) acc[i][j] = (floatx4)(0.0f);

    for (int kb = 0; kb < DIM / 32; ++kb) {
        int d0 = kb * 32;
        __syncthreads();                 // all waves done reading prev tile
        gload_lds16(gA0 + d0, lA0);
        gload_lds16(gA1 + d0, lA1);
        gload_lds16(gB0 + d0, lB0);
        gload_lds16(gB1 + d0, lB1);
        __syncthreads();                 // vmcnt(0) drain => tile resident
        short8 a[4], b[4];
#pragma unroll
        for (int i = 0; i < 4; ++i)
            a[i] = *(const short8*)&As[(wm * 64 + i * 16 + l16) * 32 + quad * 8];
#pragma unroll
        for (int j = 0; j < 4; ++j)
            b[j] = *(const short8*)&Bs[(wn * 64 + j * 16 + l16) * 32 + quad * 8];
#pragma unroll
        for (int i = 0; i < 4; ++i)
#pragma unroll
            for (int j = 0; j < 4; ++j)
                acc[i][j] = __builtin_amdgcn_mfma_f32_16x16x32_bf16(a[i], b[j], acc[i][j], 0, 0, 0);
    }

#pragma unroll
    for (int i = 0; i < 4; ++i) {
        float iqn[4], rs[4];
#pragma unroll
        for (int r = 0; r < 4; ++r) {
            iqn[r] = inv_qn[q0 + wm * 64 + i * 16 + quad * 4 + r];
            rs[r] = 0.f;
        }
#pragma unroll
        for (int j = 0; j < 4; ++j) {
            int col = n0 + wn * 64 + j * 16 + l16;
            float ikn = inv_kn[col];
#pragma unroll
            for (int r = 0; r < 4; ++r) {
                int qrow = q0 + wm * 64 + i * 16 + quad * 4 + r;
                float sc = acc[i][j][r] * iqn[r] * ikn;
                float p = __expf(sc);
                P[(size_t)qrow * NK + col] = f32_bf16(p);
                rs[r] += p;
            }
        }
#pragma unroll
        for (int r = 0; r < 4; ++r) {
            float v = rs[r];
            v += __shfl_xor(v, 1);
            v += __shfl_xor(v, 2);
            v += __shfl_xor(v, 4);
            v += __shfl_xor(v, 8);
            if (l16 == 0)
                atomicAdd(&lsum[q0 + wm * 64 + i * 16 + quad * 4 + r], v);
        }
    }
}

// ---------------------------------------------------------------------------
// GEMM 2 (split-K x4): out += (P_chunk · V_chunk) / lsum via fp32 atomics.
// grid (8, 32, 4); blockIdx.z selects k-range [z*2048, z*2048+2048).
// ---------------------------------------------------------------------------
__global__ void ctx_gemm(const unsigned short* __restrict__ P,
                         const unsigned short* __restrict__ Kt,
                         const float* __restrict__ lsum,
                         float* __restrict__ out) {
    __shared__ __align__(16) unsigned short As[128 * 32];
    __shared__ __align__(16) unsigned short Bs[128 * 32];
    int q0 = blockIdx.y * 128;
    int d0 = blockIdx.x * 128;
    int kbase = blockIdx.z * (NK / 4);
    int tid = threadIdx.x;
    int wave = tid >> 6, lane = tid & 63;
    int wm = wave >> 1, wn = wave & 1;
    int quad = lane >> 4, l16 = lane & 15;

    int srow   = wave * 32 + (lane >> 2);
    int schunk = (lane & 3) * 8;
    const unsigned short* gA0 = P + (size_t)(q0 + srow) * NK + kbase + schunk;
    const unsigned short* gA1 = gA0 + (size_t)16 * NK;
    const unsigned short* gB0 = Kt + (size_t)(d0 + srow) * NK + kbase + schunk;
    const unsigned short* gB1 = gB0 + (size_t)16 * NK;
    unsigned short* lA0 = As + wave * 32 * 32;
    unsigned short* lA1 = lA0 + 16 * 32;
    unsigned short* lB0 = Bs + wave * 32 * 32;
    unsigned short* lB1 = lB0 + 16 * 32;

    floatx4 acc[4][4];
#pragma unroll
    for (int i = 0; i < 4; ++i)
#pragma unroll
        for (int j = 0; j < 4; ++j) acc[i][j] = (floatx4)(0.0f);

    for (int kb = 0; kb < (NK / 4) / 32; ++kb) {
        int k0 = kb * 32;
        __syncthreads();
        gload_lds16(gA0 + k0, lA0);
        gload_lds16(gA1 + k0, lA1);
        gload_lds16(gB0 + k0, lB0);
        gload_lds16(gB1 + k0, lB1);
        __syncthreads();
        short8 a[4], b[4];
#pragma unroll
        for (int i = 0; i < 4; ++i)
            a[i] = *(const short8*)&As[(wm * 64 + i * 16 + l16) * 32 + quad * 8];
#pragma unroll
        for (int j = 0; j < 4; ++j)
            b[j] = *(const short8*)&Bs[(wn * 64 + j * 16 + l16) * 32 + quad * 8];
#pragma unroll
        for (int i = 0; i < 4; ++i)
#pragma unroll
            for (int j = 0; j < 4; ++j)
                acc[i][j] = __builtin_amdgcn_mfma_f32_16x16x32_bf16(a[i], b[j], acc[i][j], 0, 0, 0);
    }

#pragma unroll
    for (int i = 0; i < 4; ++i) {
        float invl[4];
#pragma unroll
        for (int r = 0; r < 4; ++r)
            invl[r] = 1.0f / lsum[q0 + wm * 64 + i * 16 + quad * 4 + r];
#pragma unroll
        for (int j = 0; j < 4; ++j) {
#pragma unroll
            for (int r = 0; r < 4; ++r) {
                int qrow = q0 + wm * 64 + i * 16 + quad * 4 + r;
                int dcol = d0 + wn * 64 + j * 16 + l16;
                atomicAdd(&out[(size_t)qrow * DIM + dcol], acc[i][j][r] * invl[r]);
            }
        }
    }
}

// ---------------------------------------------------------------------------
// Path D fallback (ws too small) — correct but slow; also a ws diagnostic.
// ---------------------------------------------------------------------------
__global__ void fused_fallback(const float* __restrict__ Q,
                               const float* __restrict__ K,
                               float* __restrict__ out) {
    int wave = threadIdx.x >> 6, lane = threadIdx.x & 63;
    int q0 = blockIdx.x * 16 + wave * 4;
    float qv[4][16], acc[4][16], iqn[4], ls[4];
#pragma unroll
    for (int r = 0; r < 4; ++r) {
        float s = 0.f;
#pragma unroll
        for (int c = 0; c < 4; ++c) {
            float4 f = *(const float4*)(Q + (size_t)(q0 + r) * DIM + c * 256 + lane * 4);
            qv[r][c * 4 + 0] = f.x; qv[r][c * 4 + 1] = f.y;
            qv[r][c * 4 + 2] = f.z; qv[r][c * 4 + 3] = f.w;
            s += f.x * f.x + f.y * f.y + f.z * f.z + f.w * f.w;
        }
#pragma unroll
        for (int off = 32; off > 0; off >>= 1) s += __shfl_xor(s, off);
        iqn[r] = 1.0f / sqrtf(s);
        ls[r] = 0.f;
#pragma unroll
        for (int t = 0; t < 16; ++t) acc[r][t] = 0.f;
    }
    for (int k = 0; k < NK; ++k) {
        const float* kr = K + (size_t)k * DIM;
        float kv[16], ss = 0.f;
#pragma unroll
        for (int c = 0; c < 4; ++c) {
            float4 f = *(const float4*)(kr + c * 256 + lane * 4);
            kv[c * 4 + 0] = f.x; kv[c * 4 + 1] = f.y;
            kv[c * 4 + 2] = f.z; kv[c * 4 + 3] = f.w;
            ss += f.x * f.x + f.y * f.y + f.z * f.z + f.w * f.w;
        }
        float d0 = 0.f, d1 = 0.f, d2 = 0.f, d3 = 0.f;
#pragma unroll
        for (int t = 0; t < 16; ++t) {
            d0 += qv[0][t] * kv[t]; d1 += qv[1][t] * kv[t];
            d2 += qv[2][t] * kv[t]; d3 += qv[3][t] * kv[t];
        }
#pragma unroll
        for (int off = 32; off > 0; off >>= 1) {
            ss += __shfl_xor(ss, off);
            d0 += __shfl_xor(d0, off); d1 += __shfl_xor(d1, off);
            d2 += __shfl_xor(d2, off); d3 += __shfl_xor(d3, off);
        }
        float ikn = 1.0f / sqrtf(ss);
        float p0 = __expf(d0 * iqn[0] * ikn), p1 = __expf(d1 * iqn[1] * ikn);
        float p2 = __expf(d2 * iqn[2] * ikn), p3 = __expf(d3 * iqn[3] * ikn);
        ls[0] += p0; ls[1] += p1; ls[2] += p2; ls[3] += p3;
#pragma unroll
        for (int t = 0; t < 16; ++t) {
            acc[0][t] += p0 * kv[t]; acc[1][t] += p1 * kv[t];
            acc[2][t] += p2 * kv[t]; acc[3][t] += p3 * kv[t];
        }
    }
#pragma unroll
    for (int r = 0; r < 4; ++r) {
        float inv = 1.0f / ls[r];
#pragma unroll
        for (int c = 0; c < 4; ++c) {
            float4 o;
            o.x = acc[r][c * 4 + 0] * inv; o.y = acc[r][c * 4 + 1] * inv;
            o.z = acc[r][c * 4 + 2] * inv; o.w = acc[r][c * 4 + 3] * inv;
            *(float4*)(out + (size_t)(q0 + r) * DIM + c * 256 + lane * 4) = o;
        }
    }
}

// ---------------------------------------------------------------------------
// launch — ws layout (confirmed ws >= 88M+64K since Path A ran in R4):
//   Kt [0,16M) overlaps Qb[0,8M)+Kb[8,24M) (dead after score_gemm)
//   P  [24M,88M) ; inv_qn/inv_kn/lsum at 88M
// ---------------------------------------------------------------------------
extern "C" void kernel_launch(void* const* d_in, const int* in_sizes, int n_in,
                              void* d_out, int out_size, void* d_ws, size_t ws_size,
                              hipStream_t stream) {
    const float* Q = (const float*)d_in[0];
    const float* K = (const float*)d_in[1];
    float* out = (float*)d_out;
    char* ws = (char*)d_ws;

    const size_t REQ_A = ((size_t)88u << 20) + 65536;
    if (ws_size >= REQ_A) {
        unsigned short* Kt = (unsigned short*)(ws);
        unsigned short* Qb = (unsigned short*)(ws);
        unsigned short* Kb = (unsigned short*)(ws + (size_t)(8u << 20));
        unsigned short* P  = (unsigned short*)(ws + (size_t)(24u << 20));
        float* inv_qn = (float*)(ws + (size_t)(88u << 20));
        float* inv_kn = (float*)(ws + (size_t)(88u << 20) + 16384);
        float* lsum   = (float*)(ws + (size_t)(88u << 20) + 49152);

        zero_out<<<NQ * DIM / 1024, 256, 0, stream>>>(out);
        prep_norm_cvt<<<NQ / 4, 256, 0, stream>>>(Q, Qb, inv_qn, lsum);
        prep_norm_cvt<<<NK / 4, 256, 0, stream>>>(K, Kb, inv_kn, nullptr);
        score_gemm<<<dim3(NK / 128, NQ / 128), 256, 0, stream>>>(Qb, Kb, inv_qn, inv_kn, P, lsum);
        transpose_cvt<<<dim3(NK / 64, DIM / 64), 256, 0, stream>>>(K, Kt);
        ctx_gemm<<<dim3(DIM / 128, NQ / 128, 4), 256, 0, stream>>>(P, Kt, lsum, out);
    } else {
        fused_fallback<<<NQ / 16, 256, 0, stream>>>(Q, K, out);
    }
}

// Round 6
// 336.763 us; speedup vs baseline: 1.0913x; 1.0038x over previous
//
// R6: score operand-swap => packed ushort4 P stores + cheap rowsum;
//     ctx split-K x8 + XCD swizzle (P-strip shared within one XCD's L2);
//     zero_out fused into Q-prep.
#include <hip/hip_runtime.h>

#define NQ 4096
#define NK 8192
#define DIM 1024

typedef __attribute__((ext_vector_type(8))) short short8;
typedef __attribute__((ext_vector_type(4))) float floatx4;
typedef unsigned int u32;
typedef __attribute__((address_space(3))) u32 lds_u32;
typedef __attribute__((address_space(1))) const u32 glb_u32;

__device__ __forceinline__ void gload_lds16(const void* g, void* l) {
    __builtin_amdgcn_global_load_lds((glb_u32*)g, (lds_u32*)l, 16, 0, 0);
}

__device__ __forceinline__ unsigned short f32_bf16(float f) {
    unsigned int u = __float_as_uint(f);
    u += 0x7fff + ((u >> 16) & 1);
    return (unsigned short)(u >> 16);
}

// ---------------------------------------------------------------------------
// Q prep + zero(out) + zero(lsum): 1024 blocks
// ---------------------------------------------------------------------------
__global__ void prep_q_zero(const float* __restrict__ Q,
                            unsigned short* __restrict__ Qb,
                            float* __restrict__ inv_qn,
                            float* __restrict__ lsum,
                            float* __restrict__ out) {
    int wave = threadIdx.x >> 6;
    int lane = threadIdx.x & 63;
    int row  = blockIdx.x * 4 + wave;
    const float* r = Q + (size_t)row * DIM;
    float s = 0.f;
#pragma unroll
    for (int c = 0; c < 4; ++c) {
        float4 f = *(const float4*)(r + c * 256 + lane * 4);
        s += f.x * f.x + f.y * f.y + f.z * f.z + f.w * f.w;
        ushort4 b;
        b.x = f32_bf16(f.x); b.y = f32_bf16(f.y);
        b.z = f32_bf16(f.z); b.w = f32_bf16(f.w);
        *(ushort4*)(Qb + (size_t)row * DIM + c * 256 + lane * 4) = b;
    }
#pragma unroll
    for (int off = 32; off > 0; off >>= 1) s += __shfl_xor(s, off);
    if (lane == 0) inv_qn[row] = 1.0f / sqrtf(s);

    // zero 4096 floats of out per block
    float4 z = make_float4(0.f, 0.f, 0.f, 0.f);
#pragma unroll
    for (int c = 0; c < 4; ++c)
        *(float4*)(out + (size_t)blockIdx.x * 4096 + c * 1024 + threadIdx.x * 4) = z;
    // zero lsum (4096 floats) with first 4 blocks
    if (blockIdx.x < 4)
        *(float4*)(lsum + blockIdx.x * 1024 + threadIdx.x * 4) = z;
}

// ---------------------------------------------------------------------------
// K prep: bf16 convert + 1/norm
// ---------------------------------------------------------------------------
__global__ void prep_norm_cvt(const float* __restrict__ src,
                              unsigned short* __restrict__ dst,
                              float* __restrict__ inv_norm) {
    int wave = threadIdx.x >> 6;
    int lane = threadIdx.x & 63;
    int row  = blockIdx.x * 4 + wave;
    const float* r = src + (size_t)row * DIM;
    float s = 0.f;
#pragma unroll
    for (int c = 0; c < 4; ++c) {
        float4 f = *(const float4*)(r + c * 256 + lane * 4);
        s += f.x * f.x + f.y * f.y + f.z * f.z + f.w * f.w;
        ushort4 b;
        b.x = f32_bf16(f.x); b.y = f32_bf16(f.y);
        b.z = f32_bf16(f.z); b.w = f32_bf16(f.w);
        *(ushort4*)(dst + (size_t)row * DIM + c * 256 + lane * 4) = b;
    }
#pragma unroll
    for (int off = 32; off > 0; off >>= 1) s += __shfl_xor(s, off);
    if (lane == 0) inv_norm[row] = 1.0f / sqrtf(s);
}

// ---------------------------------------------------------------------------
// transpose + convert: Kt[d][kn] = bf16(K[kn][d])
// ---------------------------------------------------------------------------
__global__ void transpose_cvt(const float* __restrict__ K,
                              unsigned short* __restrict__ Kt) {
    __shared__ float t[64][65];
    int kn0 = blockIdx.x * 64, d0 = blockIdx.y * 64;
    int tid = threadIdx.x;
    int r  = tid >> 4;
    int c4 = (tid & 15) * 4;
#pragma unroll
    for (int s = 0; s < 4; ++s) {
        int kk = s * 16 + r;
        float4 f = *(const float4*)(K + (size_t)(kn0 + kk) * DIM + d0 + c4);
        t[kk][c4 + 0] = f.x; t[kk][c4 + 1] = f.y;
        t[kk][c4 + 2] = f.z; t[kk][c4 + 3] = f.w;
    }
    __syncthreads();
#pragma unroll
    for (int s = 0; s < 4; ++s) {
        int dd = s * 16 + r;
        ushort4 b;
        b.x = f32_bf16(t[c4 + 0][dd]);
        b.y = f32_bf16(t[c4 + 1][dd]);
        b.z = f32_bf16(t[c4 + 2][dd]);
        b.w = f32_bf16(t[c4 + 3][dd]);
        *(ushort4*)(Kt + (size_t)(d0 + dd) * NK + kn0 + c4) = b;
    }
}

// ---------------------------------------------------------------------------
// GEMM 1 (operand-swapped): acc[i][j] = mfma(b[j], a[i], acc) holds S^T frags:
//   lane(quad,l16) reg r = S[q = q0+wm*64+i*16+l16][n = n0+wn*64+j*16+quad*4+r]
// => per lane: one q-row, 4 consecutive n-cols -> packed ushort4 P store.
// ---------------------------------------------------------------------------
__global__ void score_gemm(const unsigned short* __restrict__ Qb,
                           const unsigned short* __restrict__ Kb,
                           const float* __restrict__ inv_qn,
                           const float* __restrict__ inv_kn,
                           unsigned short* __restrict__ P,
                           float* __restrict__ lsum) {
    __shared__ __align__(16) unsigned short As[128 * 32];
    __shared__ __align__(16) unsigned short Bs[128 * 32];
    int q0 = blockIdx.y * 128;
    int n0 = blockIdx.x * 128;
    int tid = threadIdx.x;
    int wave = tid >> 6, lane = tid & 63;
    int wm = wave >> 1, wn = wave & 1;
    int quad = lane >> 4, l16 = lane & 15;

    int srow   = wave * 32 + (lane >> 2);
    int schunk = (lane & 3) * 8;
    const unsigned short* gA0 = Qb + (size_t)(q0 + srow) * DIM + schunk;
    const unsigned short* gA1 = gA0 + (size_t)16 * DIM;
    const unsigned short* gB0 = Kb + (size_t)(n0 + srow) * DIM + schunk;
    const unsigned short* gB1 = gB0 + (size_t)16 * DIM;
    unsigned short* lA0 = As + wave * 32 * 32;
    unsigned short* lA1 = lA0 + 16 * 32;
    unsigned short* lB0 = Bs + wave * 32 * 32;
    unsigned short* lB1 = lB0 + 16 * 32;

    floatx4 acc[4][4];
#pragma unroll
    for (int i = 0; i < 4; ++i)
#pragma unroll
        for (int j = 0; j < 4; ++j) acc[i][j] = (floatx4)(0.0f);

    for (int kb = 0; kb < DIM / 32; ++kb) {
        int d0 = kb * 32;
        __syncthreads();
        gload_lds16(gA0 + d0, lA0);
        gload_lds16(gA1 + d0, lA1);
        gload_lds16(gB0 + d0, lB0);
        gload_lds16(gB1 + d0, lB1);
        __syncthreads();
        short8 a[4], b[4];
#pragma unroll
        for (int i = 0; i < 4; ++i)
            a[i] = *(const short8*)&As[(wm * 64 + i * 16 + l16) * 32 + quad * 8];
#pragma unroll
        for (int j = 0; j < 4; ++j)
            b[j] = *(const short8*)&Bs[(wn * 64 + j * 16 + l16) * 32 + quad * 8];
#pragma unroll
        for (int i = 0; i < 4; ++i)
#pragma unroll
            for (int j = 0; j < 4; ++j)
                acc[i][j] = __builtin_amdgcn_mfma_f32_16x16x32_bf16(b[j], a[i], acc[i][j], 0, 0, 0);
    }

#pragma unroll
    for (int i = 0; i < 4; ++i) {
        int qrow = q0 + wm * 64 + i * 16 + l16;
        float iqn = inv_qn[qrow];
        float rs = 0.f;
#pragma unroll
        for (int j = 0; j < 4; ++j) {
            int ncol = n0 + wn * 64 + j * 16 + quad * 4;
            float4 ik = *(const float4*)&inv_kn[ncol];
            float p0 = __expf(acc[i][j][0] * iqn * ik.x);
            float p1 = __expf(acc[i][j][1] * iqn * ik.y);
            float p2 = __expf(acc[i][j][2] * iqn * ik.z);
            float p3 = __expf(acc[i][j][3] * iqn * ik.w);
            ushort4 pb;
            pb.x = f32_bf16(p0); pb.y = f32_bf16(p1);
            pb.z = f32_bf16(p2); pb.w = f32_bf16(p3);
            *(ushort4*)&P[(size_t)qrow * NK + ncol] = pb;
            rs += p0 + p1 + p2 + p3;
        }
        rs += __shfl_xor(rs, 16);
        rs += __shfl_xor(rs, 32);
        if (quad == 0) atomicAdd(&lsum[qrow], rs);
    }
}

// ---------------------------------------------------------------------------
// GEMM 2 (split-K x8, XCD-swizzled): out += (P_slice · V_slice)/lsum atomics.
// 1D grid 2048. id=(r + 8*(x + 8*ghi)); group g=(ghi<<3)|r so g%8==r => all 8
// d-blocks of a (q-tile,k-slice) group land on one XCD (assuming id%8->XCD RR)
// and share the 256 KB P-strip in that XCD's L2.
// ---------------------------------------------------------------------------
__global__ void ctx_gemm(const unsigned short* __restrict__ P,
                         const unsigned short* __restrict__ Kt,
                         const float* __restrict__ lsum,
                         float* __restrict__ out) {
    __shared__ __align__(16) unsigned short As[128 * 32];
    __shared__ __align__(16) unsigned short Bs[128 * 32];
    int id = blockIdx.x;
    int r8 = id & 7;
    int t  = id >> 3;
    int x  = t & 7;
    int g  = ((t >> 3) << 3) | r8;   // 0..255
    int y  = g & 31;
    int z  = g >> 5;                 // 0..7
    int q0 = y * 128;
    int d0 = x * 128;
    int kbase = z * (NK / 8);

    int tid = threadIdx.x;
    int wave = tid >> 6, lane = tid & 63;
    int wm = wave >> 1, wn = wave & 1;
    int quad = lane >> 4, l16 = lane & 15;

    int srow   = wave * 32 + (lane >> 2);
    int schunk = (lane & 3) * 8;
    const unsigned short* gA0 = P + (size_t)(q0 + srow) * NK + kbase + schunk;
    const unsigned short* gA1 = gA0 + (size_t)16 * NK;
    const unsigned short* gB0 = Kt + (size_t)(d0 + srow) * NK + kbase + schunk;
    const unsigned short* gB1 = gB0 + (size_t)16 * NK;
    unsigned short* lA0 = As + wave * 32 * 32;
    unsigned short* lA1 = lA0 + 16 * 32;
    unsigned short* lB0 = Bs + wave * 32 * 32;
    unsigned short* lB1 = lB0 + 16 * 32;

    floatx4 acc[4][4];
#pragma unroll
    for (int i = 0; i < 4; ++i)
#pragma unroll
        for (int j = 0; j < 4; ++j) acc[i][j] = (floatx4)(0.0f);

    for (int kb = 0; kb < (NK / 8) / 32; ++kb) {
        int k0 = kb * 32;
        __syncthreads();
        gload_lds16(gA0 + k0, lA0);
        gload_lds16(gA1 + k0, lA1);
        gload_lds16(gB0 + k0, lB0);
        gload_lds16(gB1 + k0, lB1);
        __syncthreads();
        short8 a[4], b[4];
#pragma unroll
        for (int i = 0; i < 4; ++i)
            a[i] = *(const short8*)&As[(wm * 64 + i * 16 + l16) * 32 + quad * 8];
#pragma unroll
        for (int j = 0; j < 4; ++j)
            b[j] = *(const short8*)&Bs[(wn * 64 + j * 16 + l16) * 32 + quad * 8];
#pragma unroll
        for (int i = 0; i < 4; ++i)
#pragma unroll
            for (int j = 0; j < 4; ++j)
                acc[i][j] = __builtin_amdgcn_mfma_f32_16x16x32_bf16(a[i], b[j], acc[i][j], 0, 0, 0);
    }

#pragma unroll
    for (int i = 0; i < 4; ++i) {
        float invl[4];
#pragma unroll
        for (int r = 0; r < 4; ++r)
            invl[r] = 1.0f / lsum[q0 + wm * 64 + i * 16 + quad * 4 + r];
#pragma unroll
        for (int j = 0; j < 4; ++j) {
#pragma unroll
            for (int r = 0; r < 4; ++r) {
                int qrow = q0 + wm * 64 + i * 16 + quad * 4 + r;
                int dcol = d0 + wn * 64 + j * 16 + l16;
                atomicAdd(&out[(size_t)qrow * DIM + dcol], acc[i][j][r] * invl[r]);
            }
        }
    }
}

// ---------------------------------------------------------------------------
// Path D fallback (ws too small) — correct but slow.
// ---------------------------------------------------------------------------
__global__ void fused_fallback(const float* __restrict__ Q,
                               const float* __restrict__ K,
                               float* __restrict__ out) {
    int wave = threadIdx.x >> 6, lane = threadIdx.x & 63;
    int q0 = blockIdx.x * 16 + wave * 4;
    float qv[4][16], acc[4][16], iqn[4], ls[4];
#pragma unroll
    for (int r = 0; r < 4; ++r) {
        float s = 0.f;
#pragma unroll
        for (int c = 0; c < 4; ++c) {
            float4 f = *(const float4*)(Q + (size_t)(q0 + r) * DIM + c * 256 + lane * 4);
            qv[r][c * 4 + 0] = f.x; qv[r][c * 4 + 1] = f.y;
            qv[r][c * 4 + 2] = f.z; qv[r][c * 4 + 3] = f.w;
            s += f.x * f.x + f.y * f.y + f.z * f.z + f.w * f.w;
        }
#pragma unroll
        for (int off = 32; off > 0; off >>= 1) s += __shfl_xor(s, off);
        iqn[r] = 1.0f / sqrtf(s);
        ls[r] = 0.f;
#pragma unroll
        for (int t = 0; t < 16; ++t) acc[r][t] = 0.f;
    }
    for (int k = 0; k < NK; ++k) {
        const float* kr = K + (size_t)k * DIM;
        float kv[16], ss = 0.f;
#pragma unroll
        for (int c = 0; c < 4; ++c) {
            float4 f = *(const float4*)(kr + c * 256 + lane * 4);
            kv[c * 4 + 0] = f.x; kv[c * 4 + 1] = f.y;
            kv[c * 4 + 2] = f.z; kv[c * 4 + 3] = f.w;
            ss += f.x * f.x + f.y * f.y + f.z * f.z + f.w * f.w;
        }
        float d0 = 0.f, d1 = 0.f, d2 = 0.f, d3 = 0.f;
#pragma unroll
        for (int t = 0; t < 16; ++t) {
            d0 += qv[0][t] * kv[t]; d1 += qv[1][t] * kv[t];
            d2 += qv[2][t] * kv[t]; d3 += qv[3][t] * kv[t];
        }
#pragma unroll
        for (int off = 32; off > 0; off >>= 1) {
            ss += __shfl_xor(ss, off);
            d0 += __shfl_xor(d0, off); d1 += __shfl_xor(d1, off);
            d2 += __shfl_xor(d2, off); d3 += __shfl_xor(d3, off);
        }
        float ikn = 1.0f / sqrtf(ss);
        float p0 = __expf(d0 * iqn[0] * ikn), p1 = __expf(d1 * iqn[1] * ikn);
        float p2 = __expf(d2 * iqn[2] * ikn), p3 = __expf(d3 * iqn[3] * ikn);
        ls[0] += p0; ls[1] += p1; ls[2] += p2; ls[3] += p3;
#pragma unroll
        for (int t = 0; t < 16; ++t) {
            acc[0][t] += p0 * kv[t]; acc[1][t] += p1 * kv[t];
            acc[2][t] += p2 * kv[t]; acc[3][t] += p3 * kv[t];
        }
    }
#pragma unroll
    for (int r = 0; r < 4; ++r) {
        float inv = 1.0f / ls[r];
#pragma unroll
        for (int c = 0; c < 4; ++c) {
            float4 o;
            o.x = acc[r][c * 4 + 0] * inv; o.y = acc[r][c * 4 + 1] * inv;
            o.z = acc[r][c * 4 + 2] * inv; o.w = acc[r][c * 4 + 3] * inv;
            *(float4*)(out + (size_t)(q0 + r) * DIM + c * 256 + lane * 4) = o;
        }
    }
}

// ---------------------------------------------------------------------------
// launch — ws >= 88M+64K confirmed (Path A ran in R4/R5).
//   Kt [0,16M) overlaps Qb[0,8M)+Kb[8,24M) (dead after score_gemm)
//   P  [24M,88M) ; inv_qn/inv_kn/lsum at 88M
// ---------------------------------------------------------------------------
extern "C" void kernel_launch(void* const* d_in, const int* in_sizes, int n_in,
                              void* d_out, int out_size, void* d_ws, size_t ws_size,
                              hipStream_t stream) {
    const float* Q = (const float*)d_in[0];
    const float* K = (const float*)d_in[1];
    float* out = (float*)d_out;
    char* ws = (char*)d_ws;

    const size_t REQ_A = ((size_t)88u << 20) + 65536;
    if (ws_size >= REQ_A) {
        unsigned short* Kt = (unsigned short*)(ws);
        unsigned short* Qb = (unsigned short*)(ws);
        unsigned short* Kb = (unsigned short*)(ws + (size_t)(8u << 20));
        unsigned short* P  = (unsigned short*)(ws + (size_t)(24u << 20));
        float* inv_qn = (float*)(ws + (size_t)(88u << 20));
        float* inv_kn = (float*)(ws + (size_t)(88u << 20) + 16384);
        float* lsum   = (float*)(ws + (size_t)(88u << 20) + 49152);

        prep_q_zero<<<NQ / 4, 256, 0, stream>>>(Q, Qb, inv_qn, lsum, out);
        prep_norm_cvt<<<NK / 4, 256, 0, stream>>>(K, Kb, inv_kn);
        score_gemm<<<dim3(NK / 128, NQ / 128), 256, 0, stream>>>(Qb, Kb, inv_qn, inv_kn, P, lsum);
        transpose_cvt<<<dim3(NK / 64, DIM / 64), 256, 0, stream>>>(K, Kt);
        ctx_gemm<<<2048, 256, 0, stream>>>(P, Kt, lsum, out);
    } else {
        fused_fallback<<<NQ / 16, 256, 0, stream>>>(Q, K, out);
    }
}

// Round 7
// 301.123 us; speedup vs baseline: 1.2205x; 1.1184x over previous
//
// R7: ctx = split-K x4 (R5's atomic bytes) + XCD swizzle (R6's fetch win).
//     score/prep unchanged from R6 (packed P stores, fused zero_out).
#include <hip/hip_runtime.h>

#define NQ 4096
#define NK 8192
#define DIM 1024

typedef __attribute__((ext_vector_type(8))) short short8;
typedef __attribute__((ext_vector_type(4))) float floatx4;
typedef unsigned int u32;
typedef __attribute__((address_space(3))) u32 lds_u32;
typedef __attribute__((address_space(1))) const u32 glb_u32;

__device__ __forceinline__ void gload_lds16(const void* g, void* l) {
    __builtin_amdgcn_global_load_lds((glb_u32*)g, (lds_u32*)l, 16, 0, 0);
}

__device__ __forceinline__ unsigned short f32_bf16(float f) {
    unsigned int u = __float_as_uint(f);
    u += 0x7fff + ((u >> 16) & 1);
    return (unsigned short)(u >> 16);
}

// ---------------------------------------------------------------------------
// Q prep + zero(out) + zero(lsum)
// ---------------------------------------------------------------------------
__global__ void prep_q_zero(const float* __restrict__ Q,
                            unsigned short* __restrict__ Qb,
                            float* __restrict__ inv_qn,
                            float* __restrict__ lsum,
                            float* __restrict__ out) {
    int wave = threadIdx.x >> 6;
    int lane = threadIdx.x & 63;
    int row  = blockIdx.x * 4 + wave;
    const float* r = Q + (size_t)row * DIM;
    float s = 0.f;
#pragma unroll
    for (int c = 0; c < 4; ++c) {
        float4 f = *(const float4*)(r + c * 256 + lane * 4);
        s += f.x * f.x + f.y * f.y + f.z * f.z + f.w * f.w;
        ushort4 b;
        b.x = f32_bf16(f.x); b.y = f32_bf16(f.y);
        b.z = f32_bf16(f.z); b.w = f32_bf16(f.w);
        *(ushort4*)(Qb + (size_t)row * DIM + c * 256 + lane * 4) = b;
    }
#pragma unroll
    for (int off = 32; off > 0; off >>= 1) s += __shfl_xor(s, off);
    if (lane == 0) inv_qn[row] = 1.0f / sqrtf(s);

    float4 z = make_float4(0.f, 0.f, 0.f, 0.f);
#pragma unroll
    for (int c = 0; c < 4; ++c)
        *(float4*)(out + (size_t)blockIdx.x * 4096 + c * 1024 + threadIdx.x * 4) = z;
    if (blockIdx.x < 4)
        *(float4*)(lsum + blockIdx.x * 1024 + threadIdx.x * 4) = z;
}

// ---------------------------------------------------------------------------
// K prep: bf16 convert + 1/norm
// ---------------------------------------------------------------------------
__global__ void prep_norm_cvt(const float* __restrict__ src,
                              unsigned short* __restrict__ dst,
                              float* __restrict__ inv_norm) {
    int wave = threadIdx.x >> 6;
    int lane = threadIdx.x & 63;
    int row  = blockIdx.x * 4 + wave;
    const float* r = src + (size_t)row * DIM;
    float s = 0.f;
#pragma unroll
    for (int c = 0; c < 4; ++c) {
        float4 f = *(const float4*)(r + c * 256 + lane * 4);
        s += f.x * f.x + f.y * f.y + f.z * f.z + f.w * f.w;
        ushort4 b;
        b.x = f32_bf16(f.x); b.y = f32_bf16(f.y);
        b.z = f32_bf16(f.z); b.w = f32_bf16(f.w);
        *(ushort4*)(dst + (size_t)row * DIM + c * 256 + lane * 4) = b;
    }
#pragma unroll
    for (int off = 32; off > 0; off >>= 1) s += __shfl_xor(s, off);
    if (lane == 0) inv_norm[row] = 1.0f / sqrtf(s);
}

// ---------------------------------------------------------------------------
// transpose + convert: Kt[d][kn] = bf16(K[kn][d])
// ---------------------------------------------------------------------------
__global__ void transpose_cvt(const float* __restrict__ K,
                              unsigned short* __restrict__ Kt) {
    __shared__ float t[64][65];
    int kn0 = blockIdx.x * 64, d0 = blockIdx.y * 64;
    int tid = threadIdx.x;
    int r  = tid >> 4;
    int c4 = (tid & 15) * 4;
#pragma unroll
    for (int s = 0; s < 4; ++s) {
        int kk = s * 16 + r;
        float4 f = *(const float4*)(K + (size_t)(kn0 + kk) * DIM + d0 + c4);
        t[kk][c4 + 0] = f.x; t[kk][c4 + 1] = f.y;
        t[kk][c4 + 2] = f.z; t[kk][c4 + 3] = f.w;
    }
    __syncthreads();
#pragma unroll
    for (int s = 0; s < 4; ++s) {
        int dd = s * 16 + r;
        ushort4 b;
        b.x = f32_bf16(t[c4 + 0][dd]);
        b.y = f32_bf16(t[c4 + 1][dd]);
        b.z = f32_bf16(t[c4 + 2][dd]);
        b.w = f32_bf16(t[c4 + 3][dd]);
        *(ushort4*)(Kt + (size_t)(d0 + dd) * NK + kn0 + c4) = b;
    }
}

// ---------------------------------------------------------------------------
// GEMM 1 (operand-swapped): lane owns one q-row, 4 consecutive n-cols
// -> packed ushort4 P store, 2-shuffle rowsum.
// ---------------------------------------------------------------------------
__global__ void score_gemm(const unsigned short* __restrict__ Qb,
                           const unsigned short* __restrict__ Kb,
                           const float* __restrict__ inv_qn,
                           const float* __restrict__ inv_kn,
                           unsigned short* __restrict__ P,
                           float* __restrict__ lsum) {
    __shared__ __align__(16) unsigned short As[128 * 32];
    __shared__ __align__(16) unsigned short Bs[128 * 32];
    int q0 = blockIdx.y * 128;
    int n0 = blockIdx.x * 128;
    int tid = threadIdx.x;
    int wave = tid >> 6, lane = tid & 63;
    int wm = wave >> 1, wn = wave & 1;
    int quad = lane >> 4, l16 = lane & 15;

    int srow   = wave * 32 + (lane >> 2);
    int schunk = (lane & 3) * 8;
    const unsigned short* gA0 = Qb + (size_t)(q0 + srow) * DIM + schunk;
    const unsigned short* gA1 = gA0 + (size_t)16 * DIM;
    const unsigned short* gB0 = Kb + (size_t)(n0 + srow) * DIM + schunk;
    const unsigned short* gB1 = gB0 + (size_t)16 * DIM;
    unsigned short* lA0 = As + wave * 32 * 32;
    unsigned short* lA1 = lA0 + 16 * 32;
    unsigned short* lB0 = Bs + wave * 32 * 32;
    unsigned short* lB1 = lB0 + 16 * 32;

    floatx4 acc[4][4];
#pragma unroll
    for (int i = 0; i < 4; ++i)
#pragma unroll
        for (int j = 0; j < 4; ++j) acc[i][j] = (floatx4)(0.0f);

    for (int kb = 0; kb < DIM / 32; ++kb) {
        int d0 = kb * 32;
        __syncthreads();
        gload_lds16(gA0 + d0, lA0);
        gload_lds16(gA1 + d0, lA1);
        gload_lds16(gB0 + d0, lB0);
        gload_lds16(gB1 + d0, lB1);
        __syncthreads();
        short8 a[4], b[4];
#pragma unroll
        for (int i = 0; i < 4; ++i)
            a[i] = *(const short8*)&As[(wm * 64 + i * 16 + l16) * 32 + quad * 8];
#pragma unroll
        for (int j = 0; j < 4; ++j)
            b[j] = *(const short8*)&Bs[(wn * 64 + j * 16 + l16) * 32 + quad * 8];
#pragma unroll
        for (int i = 0; i < 4; ++i)
#pragma unroll
            for (int j = 0; j < 4; ++j)
                acc[i][j] = __builtin_amdgcn_mfma_f32_16x16x32_bf16(b[j], a[i], acc[i][j], 0, 0, 0);
    }

#pragma unroll
    for (int i = 0; i < 4; ++i) {
        int qrow = q0 + wm * 64 + i * 16 + l16;
        float iqn = inv_qn[qrow];
        float rs = 0.f;
#pragma unroll
        for (int j = 0; j < 4; ++j) {
            int ncol = n0 + wn * 64 + j * 16 + quad * 4;
            float4 ik = *(const float4*)&inv_kn[ncol];
            float p0 = __expf(acc[i][j][0] * iqn * ik.x);
            float p1 = __expf(acc[i][j][1] * iqn * ik.y);
            float p2 = __expf(acc[i][j][2] * iqn * ik.z);
            float p3 = __expf(acc[i][j][3] * iqn * ik.w);
            ushort4 pb;
            pb.x = f32_bf16(p0); pb.y = f32_bf16(p1);
            pb.z = f32_bf16(p2); pb.w = f32_bf16(p3);
            *(ushort4*)&P[(size_t)qrow * NK + ncol] = pb;
            rs += p0 + p1 + p2 + p3;
        }
        rs += __shfl_xor(rs, 16);
        rs += __shfl_xor(rs, 32);
        if (quad == 0) atomicAdd(&lsum[qrow], rs);
    }
}

// ---------------------------------------------------------------------------
// GEMM 2: split-K x4 + XCD swizzle. grid 1024 (1D).
// id = r8 + 8*(x + 8*ghi); group g = ghi*8 + r8 in [0,128): y=g&31 (q-tile),
// z=g>>5 in [0,4) (k-slice); the 8 d-blocks (x) of a group share id%8 => same
// XCD => P-strip (1 MB) fetched once into that XCD's L2.
// ---------------------------------------------------------------------------
__global__ void ctx_gemm(const unsigned short* __restrict__ P,
                         const unsigned short* __restrict__ Kt,
                         const float* __restrict__ lsum,
                         float* __restrict__ out) {
    __shared__ __align__(16) unsigned short As[128 * 32];
    __shared__ __align__(16) unsigned short Bs[128 * 32];
    int id = blockIdx.x;
    int r8 = id & 7;
    int t  = id >> 3;
    int x  = t & 7;
    int g  = ((t >> 3) << 3) | r8;   // 0..127
    int y  = g & 31;
    int z  = g >> 5;                 // 0..3
    int q0 = y * 128;
    int d0 = x * 128;
    int kbase = z * (NK / 4);

    int tid = threadIdx.x;
    int wave = tid >> 6, lane = tid & 63;
    int wm = wave >> 1, wn = wave & 1;
    int quad = lane >> 4, l16 = lane & 15;

    int srow   = wave * 32 + (lane >> 2);
    int schunk = (lane & 3) * 8;
    const unsigned short* gA0 = P + (size_t)(q0 + srow) * NK + kbase + schunk;
    const unsigned short* gA1 = gA0 + (size_t)16 * NK;
    const unsigned short* gB0 = Kt + (size_t)(d0 + srow) * NK + kbase + schunk;
    const unsigned short* gB1 = gB0 + (size_t)16 * NK;
    unsigned short* lA0 = As + wave * 32 * 32;
    unsigned short* lA1 = lA0 + 16 * 32;
    unsigned short* lB0 = Bs + wave * 32 * 32;
    unsigned short* lB1 = lB0 + 16 * 32;

    floatx4 acc[4][4];
#pragma unroll
    for (int i = 0; i < 4; ++i)
#pragma unroll
        for (int j = 0; j < 4; ++j) acc[i][j] = (floatx4)(0.0f);

    for (int kb = 0; kb < (NK / 4) / 32; ++kb) {
        int k0 = kb * 32;
        __syncthreads();
        gload_lds16(gA0 + k0, lA0);
        gload_lds16(gA1 + k0, lA1);
        gload_lds16(gB0 + k0, lB0);
        gload_lds16(gB1 + k0, lB1);
        __syncthreads();
        short8 a[4], b[4];
#pragma unroll
        for (int i = 0; i < 4; ++i)
            a[i] = *(const short8*)&As[(wm * 64 + i * 16 + l16) * 32 + quad * 8];
#pragma unroll
        for (int j = 0; j < 4; ++j)
            b[j] = *(const short8*)&Bs[(wn * 64 + j * 16 + l16) * 32 + quad * 8];
#pragma unroll
        for (int i = 0; i < 4; ++i)
#pragma unroll
            for (int j = 0; j < 4; ++j)
                acc[i][j] = __builtin_amdgcn_mfma_f32_16x16x32_bf16(a[i], b[j], acc[i][j], 0, 0, 0);
    }

#pragma unroll
    for (int i = 0; i < 4; ++i) {
        float invl[4];
#pragma unroll
        for (int r = 0; r < 4; ++r)
            invl[r] = 1.0f / lsum[q0 + wm * 64 + i * 16 + quad * 4 + r];
#pragma unroll
        for (int j = 0; j < 4; ++j) {
#pragma unroll
            for (int r = 0; r < 4; ++r) {
                int qrow = q0 + wm * 64 + i * 16 + quad * 4 + r;
                int dcol = d0 + wn * 64 + j * 16 + l16;
                atomicAdd(&out[(size_t)qrow * DIM + dcol], acc[i][j][r] * invl[r]);
            }
        }
    }
}

// ---------------------------------------------------------------------------
// Path D fallback (ws too small) — correct but slow.
// ---------------------------------------------------------------------------
__global__ void fused_fallback(const float* __restrict__ Q,
                               const float* __restrict__ K,
                               float* __restrict__ out) {
    int wave = threadIdx.x >> 6, lane = threadIdx.x & 63;
    int q0 = blockIdx.x * 16 + wave * 4;
    float qv[4][16], acc[4][16], iqn[4], ls[4];
#pragma unroll
    for (int r = 0; r < 4; ++r) {
        float s = 0.f;
#pragma unroll
        for (int c = 0; c < 4; ++c) {
            float4 f = *(const float4*)(Q + (size_t)(q0 + r) * DIM + c * 256 + lane * 4);
            qv[r][c * 4 + 0] = f.x; qv[r][c * 4 + 1] = f.y;
            qv[r][c * 4 + 2] = f.z; qv[r][c * 4 + 3] = f.w;
            s += f.x * f.x + f.y * f.y + f.z * f.z + f.w * f.w;
        }
#pragma unroll
        for (int off = 32; off > 0; off >>= 1) s += __shfl_xor(s, off);
        iqn[r] = 1.0f / sqrtf(s);
        ls[r] = 0.f;
#pragma unroll
        for (int t = 0; t < 16; ++t) acc[r][t] = 0.f;
    }
    for (int k = 0; k < NK; ++k) {
        const float* kr = K + (size_t)k * DIM;
        float kv[16], ss = 0.f;
#pragma unroll
        for (int c = 0; c < 4; ++c) {
            float4 f = *(const float4*)(kr + c * 256 + lane * 4);
            kv[c * 4 + 0] = f.x; kv[c * 4 + 1] = f.y;
            kv[c * 4 + 2] = f.z; kv[c * 4 + 3] = f.w;
            ss += f.x * f.x + f.y * f.y + f.z * f.z + f.w * f.w;
        }
        float d0 = 0.f, d1 = 0.f, d2 = 0.f, d3 = 0.f;
#pragma unroll
        for (int t = 0; t < 16; ++t) {
            d0 += qv[0][t] * kv[t]; d1 += qv[1][t] * kv[t];
            d2 += qv[2][t] * kv[t]; d3 += qv[3][t] * kv[t];
        }
#pragma unroll
        for (int off = 32; off > 0; off >>= 1) {
            ss += __shfl_xor(ss, off);
            d0 += __shfl_xor(d0, off); d1 += __shfl_xor(d1, off);
            d2 += __shfl_xor(d2, off); d3 += __shfl_xor(d3, off);
        }
        float ikn = 1.0f / sqrtf(ss);
        float p0 = __expf(d0 * iqn[0] * ikn), p1 = __expf(d1 * iqn[1] * ikn);
        float p2 = __expf(d2 * iqn[2] * ikn), p3 = __expf(d3 * iqn[3] * ikn);
        ls[0] += p0; ls[1] += p1; ls[2] += p2; ls[3] += p3;
#pragma unroll
        for (int t = 0; t < 16; ++t) {
            acc[0][t] += p0 * kv[t]; acc[1][t] += p1 * kv[t];
            acc[2][t] += p2 * kv[t]; acc[3][t] += p3 * kv[t];
        }
    }
#pragma unroll
    for (int r = 0; r < 4; ++r) {
        float inv = 1.0f / ls[r];
#pragma unroll
        for (int c = 0; c < 4; ++c) {
            float4 o;
            o.x = acc[r][c * 4 + 0] * inv; o.y = acc[r][c * 4 + 1] * inv;
            o.z = acc[r][c * 4 + 2] * inv; o.w = acc[r][c * 4 + 3] * inv;
            *(float4*)(out + (size_t)(q0 + r) * DIM + c * 256 + lane * 4) = o;
        }
    }
}

// ---------------------------------------------------------------------------
// launch — ws layout: Kt [0,16M) overlaps Qb/Kb (dead after score_gemm);
// P [24M,88M); inv_qn/inv_kn/lsum at 88M.
// ---------------------------------------------------------------------------
extern "C" void kernel_launch(void* const* d_in, const int* in_sizes, int n_in,
                              void* d_out, int out_size, void* d_ws, size_t ws_size,
                              hipStream_t stream) {
    const float* Q = (const float*)d_in[0];
    const float* K = (const float*)d_in[1];
    float* out = (float*)d_out;
    char* ws = (char*)d_ws;

    const size_t REQ_A = ((size_t)88u << 20) + 65536;
    if (ws_size >= REQ_A) {
        unsigned short* Kt = (unsigned short*)(ws);
        unsigned short* Qb = (unsigned short*)(ws);
        unsigned short* Kb = (unsigned short*)(ws + (size_t)(8u << 20));
        unsigned short* P  = (unsigned short*)(ws + (size_t)(24u << 20));
        float* inv_qn = (float*)(ws + (size_t)(88u << 20));
        float* inv_kn = (float*)(ws + (size_t)(88u << 20) + 16384);
        float* lsum   = (float*)(ws + (size_t)(88u << 20) + 49152);

        prep_q_zero<<<NQ / 4, 256, 0, stream>>>(Q, Qb, inv_qn, lsum, out);
        prep_norm_cvt<<<NK / 4, 256, 0, stream>>>(K, Kb, inv_kn);
        score_gemm<<<dim3(NK / 128, NQ / 128), 256, 0, stream>>>(Qb, Kb, inv_qn, inv_kn, P, lsum);
        transpose_cvt<<<dim3(NK / 64, DIM / 64), 256, 0, stream>>>(K, Kt);
        ctx_gemm<<<1024, 256, 0, stream>>>(P, Kt, lsum, out);
    } else {
        fused_fallback<<<NQ / 16, 256, 0, stream>>>(Q, K, out);
    }
}